// Round 2
// baseline (170.257 us; speedup 1.0000x reference)
//
#include <hip/hip_runtime.h>
#include <hip/hip_bf16.h>
#include <stdint.h>

typedef __attribute__((ext_vector_type(4))) float f32x4;
typedef __attribute__((ext_vector_type(8))) short bf16x8;
typedef __attribute__((ext_vector_type(4))) short bf16x4;
typedef __attribute__((ext_vector_type(4))) unsigned int u32x4;

__device__ __forceinline__ unsigned short f2bf_rne(float f) {
  union { float f; unsigned int u; } v; v.f = f;
  unsigned int r = v.u + 0x7FFFu + ((v.u >> 16) & 1u);
  return (unsigned short)(r >> 16);
}
__device__ __forceinline__ float bf2f(unsigned short s) {
  union { float f; unsigned int u; } v; v.u = ((unsigned int)s) << 16;
  return v.f;
}

// ---------------------------------------------------------------------------
// K1: per-batch Gram G = X X^T, exact via split bf16: G = H H^T + H L^T + L H^T
// (x = hi + lo, LL^T ~1e-4 dropped). Also writes x_hi (bf16 of x) for K3.
// grid (16 n-chunks, 16 b) x 1024 thr. LDS row per c: H (32 k) | L (32 k),
// 128 B rows, XOR-swizzled 16B slots. Same k-map for A and B frags -> robust.
// ---------------------------------------------------------------------------
__global__ __launch_bounds__(1024) void k_gram(const float* __restrict__ x,
                                               unsigned short* __restrict__ x_hi,
                                               float* __restrict__ G) {
  __shared__ __align__(16) unsigned char lds[256 * 128];
  const int b = blockIdx.y;
  const int n0 = blockIdx.x << 8;
  const int t = threadIdx.x;
  const int lane = t & 63;
  const int w = t >> 6;
  const int wm = (w >> 2) << 6;
  const int wn = (w & 3) << 6;
  const int c_ld = t >> 2;
  const int noct = t & 3;
  const int lrow = lane & 15;
  const int lkg = lane >> 4;

  f32x4 acc[4][4];
#pragma unroll
  for (int i = 0; i < 4; i++)
#pragma unroll
    for (int j = 0; j < 4; j++) acc[i][j] = (f32x4){0.f, 0.f, 0.f, 0.f};

  for (int sub = 0; sub < 8; sub++) {
    const size_t gidx = (((size_t)(b * 256 + c_ld)) << 12) + n0 + (sub << 5) + (noct << 3);
    f32x4 v0 = *(const f32x4*)(x + gidx);
    f32x4 v1 = *(const f32x4*)(x + gidx + 4);
    float vv[8] = {v0[0], v0[1], v0[2], v0[3], v1[0], v1[1], v1[2], v1[3]};
    unsigned short hi[8], lo[8];
#pragma unroll
    for (int j = 0; j < 8; j++) {
      hi[j] = f2bf_rne(vv[j]);
      lo[j] = f2bf_rne(vv[j] - bf2f(hi[j]));
    }
    u32x4 hw = {(unsigned)hi[0] | ((unsigned)hi[1] << 16),
                (unsigned)hi[2] | ((unsigned)hi[3] << 16),
                (unsigned)hi[4] | ((unsigned)hi[5] << 16),
                (unsigned)hi[6] | ((unsigned)hi[7] << 16)};
    u32x4 lw = {(unsigned)lo[0] | ((unsigned)lo[1] << 16),
                (unsigned)lo[2] | ((unsigned)lo[3] << 16),
                (unsigned)lo[4] | ((unsigned)lo[5] << 16),
                (unsigned)lo[6] | ((unsigned)lo[7] << 16)};
    *(u32x4*)(x_hi + gidx) = hw;

    __syncthreads();  // previous tile's reads done before overwrite
    const int swz = (c_ld & 7) << 4;
    *(u32x4*)(lds + c_ld * 128 + (((noct << 4)) ^ swz)) = hw;       // H region
    *(u32x4*)(lds + c_ld * 128 + ((64 + (noct << 4)) ^ swz)) = lw;  // L region
    __syncthreads();

    bf16x8 bh[4], bl[4];
#pragma unroll
    for (int nf = 0; nf < 4; nf++) {
      int col = wn + (nf << 4) + lrow;
      int cs = (col & 7) << 4;
      bh[nf] = *(const bf16x8*)(lds + col * 128 + (((lkg << 4)) ^ cs));
      bl[nf] = *(const bf16x8*)(lds + col * 128 + ((64 + (lkg << 4)) ^ cs));
    }
#pragma unroll
    for (int mf = 0; mf < 4; mf++) {
      int row = wm + (mf << 4) + lrow;
      int rs = (row & 7) << 4;
      bf16x8 ah = *(const bf16x8*)(lds + row * 128 + (((lkg << 4)) ^ rs));
      bf16x8 al = *(const bf16x8*)(lds + row * 128 + ((64 + (lkg << 4)) ^ rs));
#pragma unroll
      for (int nf = 0; nf < 4; nf++) {
        acc[mf][nf] = __builtin_amdgcn_mfma_f32_16x16x32_bf16(ah, bh[nf], acc[mf][nf], 0, 0, 0);
        acc[mf][nf] = __builtin_amdgcn_mfma_f32_16x16x32_bf16(ah, bl[nf], acc[mf][nf], 0, 0, 0);
        acc[mf][nf] = __builtin_amdgcn_mfma_f32_16x16x32_bf16(al, bh[nf], acc[mf][nf], 0, 0, 0);
      }
    }
  }

  float* Gb = G + ((size_t)b << 16);
#pragma unroll
  for (int mf = 0; mf < 4; mf++)
#pragma unroll
    for (int nf = 0; nf < 4; nf++) {
      int col = wn + (nf << 4) + lrow;
#pragma unroll
      for (int r = 0; r < 4; r++) {
        int row = wm + (mf << 4) + (lkg << 2) + r;
        atomicAdd(Gb + row * 256 + col, acc[mf][nf][r]);
      }
    }
}

// ---------------------------------------------------------------------------
// K2: scores = Wq_h G Wk_h^T / sqrt(8), softmax rows, attn_weights out,
// W_out[d*8+h,:] = A·Wv_h + Wv[d*8+h,:] (bf16). grid (8 h, 16 b, 2 dgrp) x 512.
// Rotated LDS rows (idx = r*256 + (c+r)&255) to kill bank conflicts.
// ---------------------------------------------------------------------------
__global__ __launch_bounds__(512) void k_scores(const float* __restrict__ wq,
                                                const float* __restrict__ wk,
                                                const float* __restrict__ wv,
                                                const float* __restrict__ G,
                                                float* __restrict__ attn,
                                                unsigned short* __restrict__ Wout) {
  __shared__ float Wbuf[32 * 256];
  __shared__ float Tbuf[16 * 256];
  __shared__ float Abuf[16 * 32];
  const int h = blockIdx.x, b = blockIdx.y, dg = blockIdx.z;
  const int t = threadIdx.x;

  for (int i = t; i < 16 * 256; i += 512) {
    int r = i >> 8, c = i & 255;
    Wbuf[r * 256 + ((c + r) & 255)] = wq[(h * 32 + dg * 16 + r) * 256 + c];
  }
  __syncthreads();

  const int cp = t & 255, half = t >> 8;
  float T[8];
#pragma unroll
  for (int j = 0; j < 8; j++) T[j] = 0.f;
  const float* Gbc = G + ((size_t)b << 16) + cp;
  for (int c = 0; c < 256; c++) {
    float g = Gbc[c * 256];
#pragma unroll
    for (int j = 0; j < 8; j++) {
      int dl = half * 8 + j;
      T[j] = fmaf(Wbuf[dl * 256 + ((c + dl) & 255)], g, T[j]);
    }
  }
  __syncthreads();
#pragma unroll
  for (int j = 0; j < 8; j++) {
    int dl = half * 8 + j;
    Tbuf[dl * 256 + ((cp + dl) & 255)] = T[j];
  }
  for (int i = t; i < 32 * 256; i += 512) {
    int r = i >> 8, c = i & 255;
    Wbuf[r * 256 + ((c + r) & 255)] = wk[(h * 32 + r) * 256 + c];
  }
  __syncthreads();

  const int dls = t >> 5, es = t & 31;
  float s = 0.f;
  for (int c = 0; c < 256; c++)
    s = fmaf(Tbuf[dls * 256 + ((c + dls) & 255)], Wbuf[es * 256 + ((c + es) & 255)], s);
  s *= 0.35355339059327379f;  // 1/sqrt(8)

  float m = s;
#pragma unroll
  for (int off = 1; off < 32; off <<= 1) m = fmaxf(m, __shfl_xor(m, off));
  float p = expf(s - m);
  float su = p;
#pragma unroll
  for (int off = 1; off < 32; off <<= 1) su += __shfl_xor(su, off);
  float a = p / su;
  attn[(((b * 8 + h) * 32) + dg * 16 + dls) * 32 + es] = a;
  Abuf[dls * 32 + es] = a;
  __syncthreads();

  for (int i = t; i < 32 * 256; i += 512) {
    int r = i >> 8, c = i & 255;
    Wbuf[r * 256 + ((c + r) & 255)] = wv[(h * 32 + r) * 256 + c];
  }
  __syncthreads();

#pragma unroll
  for (int j = 0; j < 8; j++) {
    int dl = half * 8 + j;
    int d = dg * 16 + dl;
    float acc2 = 0.f;
#pragma unroll
    for (int e = 0; e < 32; e++)
      acc2 = fmaf(Abuf[dl * 32 + e], Wbuf[e * 256 + ((cp + e) & 255)], acc2);
    int co = d * 8 + h;
    Wout[(((size_t)(b * 256 + co)) << 8) + cp] = f2bf_rne(acc2 + wv[co * 256 + cp]);
  }
}

// ---------------------------------------------------------------------------
// K3: out[b] = W_out_b (bf16) x x_hi[b] (bf16), fp32 out.
// grid (32 n-chunks, 16 b) x 512 thr (8 waves, 4M x 2N, wave tile 64x64).
// B staged via global_load_lds into subtiled [c][n] LDS (cblk even-first
// ordering); B-frags via ds_read_b64_tr_b16 x2 with PER-LANE group base
// (bt0 + Wblk*1024 + lane*8 — the m156/HK measured pattern). A from L2.
// ---------------------------------------------------------------------------
__device__ __forceinline__ void glds16(const void* gsrc, void* ldst) {
  typedef const __attribute__((address_space(1))) uint32_t GU;
  typedef __attribute__((address_space(3))) uint32_t LU;
  GU* g = reinterpret_cast<GU*>(reinterpret_cast<uintptr_t>(gsrc));
  LU* l = reinterpret_cast<LU*>(static_cast<uint32_t>(reinterpret_cast<uintptr_t>(ldst)));
  __builtin_amdgcn_global_load_lds(g, l, 16, 0, 0);
}

__global__ __launch_bounds__(512) void k_out(const unsigned short* __restrict__ x_hi,
                                             const unsigned short* __restrict__ Wout,
                                             float* __restrict__ out) {
  __shared__ __align__(16) unsigned short Bt[4096];  // 32c x 128n, subtiled
  const int b = blockIdx.y;
  const int nb = blockIdx.x << 7;
  const int t = threadIdx.x;
  const int lane = t & 63;
  const int w = t >> 6;
  const int wm = (w >> 1) << 6;
  const int wn = (w & 1) << 6;
  const int lrow = lane & 15;
  const int lkg = lane >> 4;

  f32x4 acc[4][4];
#pragma unroll
  for (int i = 0; i < 4; i++)
#pragma unroll
    for (int j = 0; j < 4; j++) acc[i][j] = (f32x4){0.f, 0.f, 0.f, 0.f};

  // staging lane map: linear LDS dest <- permuted global src (m173 pattern)
  const int pos = lane >> 3;
  const int cblk = 2 * (pos & 3) + (pos >> 2);  // even cblks first, then odd
  const int ctil = cblk * 4 + ((lane & 7) >> 1);
  const int noff = (lane & 1) << 3;
  const unsigned short* gb = x_hi + (((size_t)b) << 20);
  const unsigned int bt0 = (unsigned int)(uintptr_t)(&Bt[0]);

  for (int kt = 0; kt < 8; kt++) {
    __syncthreads();
    glds16(gb + (((size_t)(kt * 32 + ctil)) << 12) + nb + (w << 4) + noff, &Bt[w * 512]);
    __syncthreads();  // vmcnt(0) drained here by compiler

    bf16x8 afr[4];
    const unsigned short* wrow = Wout + (((size_t)(b * 256)) << 8) + kt * 32 + (lkg << 3);
#pragma unroll
    for (int mf = 0; mf < 4; mf++) {
      int co = wm + (mf << 4) + lrow;
      afr[mf] = *(const bf16x8*)(wrow + ((size_t)co << 8));
    }

    bf16x4 t0[4], t1[4];
#pragma unroll
    for (int nf = 0; nf < 4; nf++) {
      unsigned int base = bt0 + (unsigned int)((((wn >> 4) + nf)) << 10) + (lane << 3);
      asm volatile("ds_read_b64_tr_b16 %0, %1" : "=v"(t0[nf]) : "v"(base) : "memory");
      asm volatile("ds_read_b64_tr_b16 %0, %1 offset:512" : "=v"(t1[nf]) : "v"(base) : "memory");
    }
    asm volatile("s_waitcnt lgkmcnt(0)" ::: "memory");
    __builtin_amdgcn_sched_barrier(0);

    bf16x8 bfr[4];
#pragma unroll
    for (int nf = 0; nf < 4; nf++) {
      bfr[nf][0] = t0[nf][0]; bfr[nf][1] = t0[nf][1];
      bfr[nf][2] = t0[nf][2]; bfr[nf][3] = t0[nf][3];
      bfr[nf][4] = t1[nf][0]; bfr[nf][5] = t1[nf][1];
      bfr[nf][6] = t1[nf][2]; bfr[nf][7] = t1[nf][3];
    }
#pragma unroll
    for (int mf = 0; mf < 4; mf++)
#pragma unroll
      for (int nf = 0; nf < 4; nf++)
        acc[mf][nf] = __builtin_amdgcn_mfma_f32_16x16x32_bf16(afr[mf], bfr[nf], acc[mf][nf], 0, 0, 0);
  }

  float* ob = out + (((size_t)b) << 20) + nb;
#pragma unroll
  for (int mf = 0; mf < 4; mf++)
#pragma unroll
    for (int nf = 0; nf < 4; nf++) {
      int col = wn + (nf << 4) + lrow;
#pragma unroll
      for (int r = 0; r < 4; r++) {
        int row = wm + (mf << 4) + (lkg << 2) + r;
        ob[((size_t)row << 12) + col] = acc[mf][nf][r];
      }
    }
}

// ---------------------------------------------------------------------------
extern "C" void kernel_launch(void* const* d_in, const int* in_sizes, int n_in,
                              void* d_out, int out_size, void* d_ws, size_t ws_size,
                              hipStream_t stream) {
  const float* x = (const float*)d_in[0];
  const float* wq = (const float*)d_in[1];
  const float* wk = (const float*)d_in[2];
  const float* wv = (const float*)d_in[3];
  float* out = (float*)d_out;
  float* attn = out + (size_t)16 * 256 * 4096;

  char* ws = (char*)d_ws;
  unsigned short* x_hi = (unsigned short*)ws;                       // 33,554,432 B
  float* G = (float*)(ws + 33554432);                               //  4,194,304 B
  unsigned short* Wout = (unsigned short*)(ws + 33554432 + 4194304);//  2,097,152 B

  hipMemsetAsync(G, 0, (size_t)16 * 256 * 256 * sizeof(float), stream);
  k_gram<<<dim3(16, 16), dim3(1024), 0, stream>>>(x, x_hi, G);
  k_scores<<<dim3(8, 16, 2), dim3(512), 0, stream>>>(wq, wk, wv, G, attn, Wout);
  k_out<<<dim3(32, 16), dim3(512), 0, stream>>>(x_hi, Wout, out);
}

// Round 3
// 111.709 us; speedup vs baseline: 1.5241x; 1.5241x over previous
//
#include <hip/hip_runtime.h>
#include <hip/hip_bf16.h>
#include <stdint.h>

typedef __attribute__((ext_vector_type(4))) float f32x4;
typedef __attribute__((ext_vector_type(8))) short bf16x8;
typedef __attribute__((ext_vector_type(4))) short bf16x4;
typedef __attribute__((ext_vector_type(4))) unsigned int u32x4;

__device__ __forceinline__ unsigned short f2bf_rne(float f) {
  union { float f; unsigned int u; } v; v.f = f;
  unsigned int r = v.u + 0x7FFFu + ((v.u >> 16) & 1u);
  return (unsigned short)(r >> 16);
}
__device__ __forceinline__ float bf2f(unsigned short s) {
  union { float f; unsigned int u; } v; v.u = ((unsigned int)s) << 16;
  return v.f;
}

// ---------------------------------------------------------------------------
// K1: per-batch Gram partials: Gpart[chunk][b] = X_slice X_slice^T via split
// bf16 (H H^T + H L^T + L H^T). NO atomics: plain coalesced stores into the
// (temporarily dead) out buffer. T14: next-sub x loads issued under MFMA.
// grid (16 n-chunks, 16 b) x 1024 thr.
// ---------------------------------------------------------------------------
__global__ __launch_bounds__(1024) void k_gram(const float* __restrict__ x,
                                               float* __restrict__ Gpart) {
  __shared__ __align__(16) unsigned char lds[256 * 128];
  const int b = blockIdx.y;
  const int n0 = blockIdx.x << 8;
  const int t = threadIdx.x;
  const int lane = t & 63;
  const int w = t >> 6;
  const int wm = (w >> 2) << 6;
  const int wn = (w & 3) << 6;
  const int c_ld = t >> 2;
  const int noct = t & 3;
  const int lrow = lane & 15;
  const int lkg = lane >> 4;

  f32x4 acc[4][4];
#pragma unroll
  for (int i = 0; i < 4; i++)
#pragma unroll
    for (int j = 0; j < 4; j++) acc[i][j] = (f32x4){0.f, 0.f, 0.f, 0.f};

  const float* gx = x + (((size_t)(b * 256 + c_ld)) << 12) + n0 + (noct << 3);
  f32x4 v0 = *(const f32x4*)(gx);
  f32x4 v1 = *(const f32x4*)(gx + 4);

  for (int sub = 0; sub < 8; sub++) {
    float vv[8] = {v0[0], v0[1], v0[2], v0[3], v1[0], v1[1], v1[2], v1[3]};
    unsigned short hi[8], lo[8];
#pragma unroll
    for (int j = 0; j < 8; j++) {
      hi[j] = f2bf_rne(vv[j]);
      lo[j] = f2bf_rne(vv[j] - bf2f(hi[j]));
    }
    u32x4 hw = {(unsigned)hi[0] | ((unsigned)hi[1] << 16),
                (unsigned)hi[2] | ((unsigned)hi[3] << 16),
                (unsigned)hi[4] | ((unsigned)hi[5] << 16),
                (unsigned)hi[6] | ((unsigned)hi[7] << 16)};
    u32x4 lw = {(unsigned)lo[0] | ((unsigned)lo[1] << 16),
                (unsigned)lo[2] | ((unsigned)lo[3] << 16),
                (unsigned)lo[4] | ((unsigned)lo[5] << 16),
                (unsigned)lo[6] | ((unsigned)lo[7] << 16)};

    __syncthreads();  // previous tile's MFMA reads done before overwrite
    const int swz = (c_ld & 7) << 4;
    *(u32x4*)(lds + c_ld * 128 + (((noct << 4)) ^ swz)) = hw;       // H region
    *(u32x4*)(lds + c_ld * 128 + ((64 + (noct << 4)) ^ swz)) = lw;  // L region
    __syncthreads();

    // prefetch next sub's x under the MFMA section (T14 split)
    if (sub < 7) {
      v0 = *(const f32x4*)(gx + ((sub + 1) << 5));
      v1 = *(const f32x4*)(gx + ((sub + 1) << 5) + 4);
    }

    bf16x8 bh[4], bl[4];
#pragma unroll
    for (int nf = 0; nf < 4; nf++) {
      int col = wn + (nf << 4) + lrow;
      int cs = (col & 7) << 4;
      bh[nf] = *(const bf16x8*)(lds + col * 128 + (((lkg << 4)) ^ cs));
      bl[nf] = *(const bf16x8*)(lds + col * 128 + ((64 + (lkg << 4)) ^ cs));
    }
#pragma unroll
    for (int mf = 0; mf < 4; mf++) {
      int row = wm + (mf << 4) + lrow;
      int rs = (row & 7) << 4;
      bf16x8 ah = *(const bf16x8*)(lds + row * 128 + (((lkg << 4)) ^ rs));
      bf16x8 al = *(const bf16x8*)(lds + row * 128 + ((64 + (lkg << 4)) ^ rs));
#pragma unroll
      for (int nf = 0; nf < 4; nf++) {
        acc[mf][nf] = __builtin_amdgcn_mfma_f32_16x16x32_bf16(ah, bh[nf], acc[mf][nf], 0, 0, 0);
        acc[mf][nf] = __builtin_amdgcn_mfma_f32_16x16x32_bf16(ah, bl[nf], acc[mf][nf], 0, 0, 0);
        acc[mf][nf] = __builtin_amdgcn_mfma_f32_16x16x32_bf16(al, bh[nf], acc[mf][nf], 0, 0, 0);
      }
    }
  }

  float* Gp = Gpart + (((size_t)(blockIdx.x * 16 + b)) << 16);
#pragma unroll
  for (int mf = 0; mf < 4; mf++)
#pragma unroll
    for (int nf = 0; nf < 4; nf++) {
      int col = wn + (nf << 4) + lrow;
#pragma unroll
      for (int r = 0; r < 4; r++) {
        int row = wm + (mf << 4) + (lkg << 2) + r;
        Gp[row * 256 + col] = acc[mf][nf][r];
      }
    }
}

// ---------------------------------------------------------------------------
// K1b: G = sum over 16 chunk-partials. 67 MB read (L3-hot), 4 MB write.
// ---------------------------------------------------------------------------
__global__ __launch_bounds__(256) void k_reduce(const float* __restrict__ Gpart,
                                                float* __restrict__ G) {
  const size_t i = ((((size_t)blockIdx.x << 8) + threadIdx.x) << 2);
  f32x4 s = *(const f32x4*)(Gpart + i);
#pragma unroll
  for (int ch = 1; ch < 16; ch++)
    s += *(const f32x4*)(Gpart + (((size_t)ch) << 20) + i);
  *(f32x4*)(G + i) = s;
}

// ---------------------------------------------------------------------------
// K2: T = Wq_rows·G (c-split over 8 waves, Wq in regs + shfl, G read ONCE),
// LDS partial-reduce; scores = T·Wk^T (f32x4 dots) + softmax -> attn;
// Wout rows via shfl(A) + coalesced Wv rows. grid (8 h, 16 b, 2 dg) x 512.
// ---------------------------------------------------------------------------
__global__ __launch_bounds__(512) void k_scores(const float* __restrict__ wq,
                                                const float* __restrict__ wk,
                                                const float* __restrict__ wv,
                                                const float* __restrict__ G,
                                                float* __restrict__ attn,
                                                unsigned short* __restrict__ Wout) {
  __shared__ float part[8][16][256];  // 128 KB; part[0] becomes T after reduce
  const int h = blockIdx.x, b = blockIdx.y, dg = blockIdx.z;
  const int t = threadIdx.x, lane = t & 63, w = t >> 6;

  // ---- Phase 1: T[d][cp] = sum_c Wq[h*32+dg*16+d][c] * G[b][c][cp] ----
  float wqp[8];
  const float* wqb = wq + (size_t)(h * 32 + dg * 16) * 256 + w * 32;
#pragma unroll
  for (int r = 0; r < 8; r++)
    wqp[r] = wqb[(2 * r + (lane >> 5)) * 256 + (lane & 31)];

  f32x4 tp[16];
#pragma unroll
  for (int d = 0; d < 16; d++) tp[d] = (f32x4){0.f, 0.f, 0.f, 0.f};

  const float* Gb = G + ((size_t)b << 16) + (size_t)(w * 32) * 256 + (lane << 2);
  for (int s = 0; s < 32; s++) {
    f32x4 g = *(const f32x4*)(Gb + s * 256);
#pragma unroll
    for (int d = 0; d < 16; d++) {
      float wval = __shfl(wqp[d >> 1], ((d & 1) << 5) | s);
      tp[d] += g * wval;
    }
  }
#pragma unroll
  for (int d = 0; d < 16; d++)
    *(f32x4*)&part[w][d][lane << 2] = tp[d];
  __syncthreads();

  // in-place reduce into part[0]: each thread owns 2 f32x4 output slots
#pragma unroll
  for (int u = 0; u < 2; u++) {
    int o = t * 2 + u;  // [0,1024) = 16 d x 64 quads
    int d = o >> 6, q = (o & 63) << 2;
    f32x4 s = *(f32x4*)&part[0][d][q];
#pragma unroll
    for (int w2 = 1; w2 < 8; w2++) s += *(f32x4*)&part[w2][d][q];
    *(f32x4*)&part[0][d][q] = s;
  }
  __syncthreads();
  const float* Tb = &part[0][0][0];

  // ---- Phase 2: scores + softmax (thread = (dls = t>>5, es = t&31)) ----
  const int dls = t >> 5, es = t & 31;
  f32x4 sa = {0.f, 0.f, 0.f, 0.f};
  const float* Tr = Tb + dls * 256;
  const float* wkr = wk + (size_t)(h * 32 + es) * 256;
  for (int c4 = 0; c4 < 64; c4++)
    sa += *(const f32x4*)(Tr + (c4 << 2)) * *(const f32x4*)(wkr + (c4 << 2));
  float s = (sa[0] + sa[1] + sa[2] + sa[3]) * 0.35355339059327379f;

  float m = s;
#pragma unroll
  for (int off = 1; off < 32; off <<= 1) m = fmaxf(m, __shfl_xor(m, off));
  float p = expf(s - m);
  float su = p;
#pragma unroll
  for (int off = 1; off < 32; off <<= 1) su += __shfl_xor(su, off);
  float a = p / su;
  attn[(((b * 8 + h) * 32) + dg * 16 + dls) * 32 + es] = a;

  // ---- Phase 3: wave w owns rows {2w, 2w+1}; A stays in lanes ----
  f32x4 o0 = {0.f, 0.f, 0.f, 0.f}, o1 = {0.f, 0.f, 0.f, 0.f};
  const float* wvh = wv + (size_t)(h * 32) * 256 + (lane << 2);
  for (int e = 0; e < 32; e++) {
    float a0 = __shfl(a, e);
    float a1 = __shfl(a, 32 + e);
    f32x4 vv = *(const f32x4*)(wvh + e * 256);
    o0 += vv * a0;
    o1 += vv * a1;
  }
  const int d0 = dg * 16 + 2 * w;
  const int co0 = d0 * 8 + h, co1 = (d0 + 1) * 8 + h;
  o0 += *(const f32x4*)(wv + (size_t)co0 * 256 + (lane << 2));
  o1 += *(const f32x4*)(wv + (size_t)co1 * 256 + (lane << 2));
  bf16x4 p0, p1;
#pragma unroll
  for (int j = 0; j < 4; j++) {
    p0[j] = (short)f2bf_rne(o0[j]);
    p1[j] = (short)f2bf_rne(o1[j]);
  }
  *(bf16x4*)(Wout + ((size_t)(b * 256 + co0) << 8) + (lane << 2)) = p0;
  *(bf16x4*)(Wout + ((size_t)(b * 256 + co1) << 8) + (lane << 2)) = p1;
}

// ---------------------------------------------------------------------------
// K3: out[b] = W_out_b (bf16) x bf16(x[b]), fp32 out. x read fp32 (L3-hot),
// converted in-kernel, ds_write_b128 to the SAME linear layout glds16 used;
// tr_b16 B-frag path unchanged. Next k-tile x prefetched under MFMA.
// grid (32 n-chunks, 16 b) x 512 thr.
// ---------------------------------------------------------------------------
__global__ __launch_bounds__(512) void k_out(const float* __restrict__ x,
                                             const unsigned short* __restrict__ Wout,
                                             float* __restrict__ out) {
  __shared__ __align__(16) unsigned short Bt[4096];  // 32c x 128n, subtiled
  const int b = blockIdx.y;
  const int nb = blockIdx.x << 7;
  const int t = threadIdx.x;
  const int lane = t & 63;
  const int w = t >> 6;
  const int wm = (w >> 1) << 6;
  const int wn = (w & 1) << 6;
  const int lrow = lane & 15;
  const int lkg = lane >> 4;

  f32x4 acc[4][4];
#pragma unroll
  for (int i = 0; i < 4; i++)
#pragma unroll
    for (int j = 0; j < 4; j++) acc[i][j] = (f32x4){0.f, 0.f, 0.f, 0.f};

  // staging lane map (m173 pattern): linear LDS dest <- permuted global src
  const int pos = lane >> 3;
  const int cblk = 2 * (pos & 3) + (pos >> 2);  // even cblks first, then odd
  const int ctil = cblk * 4 + ((lane & 7) >> 1);
  const int noff = (lane & 1) << 3;
  const float* gxb = x + (((size_t)b) << 20) + (size_t)ctil * 4096 + nb + (w << 4) + noff;
  const unsigned int bt0 = (unsigned int)(uintptr_t)(&Bt[0]);

  f32x4 xa = *(const f32x4*)(gxb);
  f32x4 xb = *(const f32x4*)(gxb + 4);

  for (int kt = 0; kt < 8; kt++) {
    __syncthreads();  // prior MFMA reads of Bt done
    bf16x8 pk;
#pragma unroll
    for (int j = 0; j < 4; j++) {
      pk[j] = (short)f2bf_rne(xa[j]);
      pk[4 + j] = (short)f2bf_rne(xb[j]);
    }
    *(bf16x8*)(Bt + (w << 9) + (lane << 3)) = pk;
    __syncthreads();

    if (kt < 7) {  // prefetch next k-tile under MFMA
      const float* nx = gxb + (((size_t)(kt + 1)) << 17);
      xa = *(const f32x4*)(nx);
      xb = *(const f32x4*)(nx + 4);
    }

    bf16x8 afr[4];
    const unsigned short* wrow = Wout + (((size_t)(b * 256)) << 8) + kt * 32 + (lkg << 3);
#pragma unroll
    for (int mf = 0; mf < 4; mf++) {
      int co = wm + (mf << 4) + lrow;
      afr[mf] = *(const bf16x8*)(wrow + ((size_t)co << 8));
    }

    bf16x4 t0[4], t1[4];
#pragma unroll
    for (int nf = 0; nf < 4; nf++) {
      unsigned int base = bt0 + (unsigned int)((((wn >> 4) + nf)) << 10) + (lane << 3);
      asm volatile("ds_read_b64_tr_b16 %0, %1" : "=v"(t0[nf]) : "v"(base) : "memory");
      asm volatile("ds_read_b64_tr_b16 %0, %1 offset:512" : "=v"(t1[nf]) : "v"(base) : "memory");
    }
    asm volatile("s_waitcnt lgkmcnt(0)" ::: "memory");
    __builtin_amdgcn_sched_barrier(0);

    bf16x8 bfr[4];
#pragma unroll
    for (int nf = 0; nf < 4; nf++) {
      bfr[nf][0] = t0[nf][0]; bfr[nf][1] = t0[nf][1];
      bfr[nf][2] = t0[nf][2]; bfr[nf][3] = t0[nf][3];
      bfr[nf][4] = t1[nf][0]; bfr[nf][5] = t1[nf][1];
      bfr[nf][6] = t1[nf][2]; bfr[nf][7] = t1[nf][3];
    }
#pragma unroll
    for (int mf = 0; mf < 4; mf++)
#pragma unroll
      for (int nf = 0; nf < 4; nf++)
        acc[mf][nf] = __builtin_amdgcn_mfma_f32_16x16x32_bf16(afr[mf], bfr[nf], acc[mf][nf], 0, 0, 0);
  }

  float* ob = out + (((size_t)b) << 20) + nb;
#pragma unroll
  for (int mf = 0; mf < 4; mf++)
#pragma unroll
    for (int nf = 0; nf < 4; nf++) {
      int col = wn + (nf << 4) + lrow;
#pragma unroll
      for (int r = 0; r < 4; r++) {
        int row = wm + (mf << 4) + (lkg << 2) + r;
        ob[((size_t)row << 12) + col] = acc[mf][nf][r];
      }
    }
}

// ---------------------------------------------------------------------------
extern "C" void kernel_launch(void* const* d_in, const int* in_sizes, int n_in,
                              void* d_out, int out_size, void* d_ws, size_t ws_size,
                              hipStream_t stream) {
  const float* x = (const float*)d_in[0];
  const float* wq = (const float*)d_in[1];
  const float* wk = (const float*)d_in[2];
  const float* wv = (const float*)d_in[3];
  float* out = (float*)d_out;
  float* attn = out + (size_t)16 * 256 * 4096;

  // Gram partials live in the (dead-until-K3) out region: 16 x 4 MB = exactly
  // the 67.1 MB out area; attn tail is disjoint. All consumed before K3 writes.
  float* Gpart = out;

  char* ws = (char*)d_ws;
  float* G = (float*)ws;                                  // 4 MB
  unsigned short* Wout = (unsigned short*)(ws + (4 << 20));  // 2 MB

  k_gram<<<dim3(16, 16), dim3(1024), 0, stream>>>(x, Gpart);
  k_reduce<<<dim3(1024), dim3(256), 0, stream>>>(Gpart, G);
  k_scores<<<dim3(8, 16, 2), dim3(512), 0, stream>>>(wq, wk, wv, G, attn, Wout);
  k_out<<<dim3(32, 16), dim3(512), 0, stream>>>(x, Wout, out);
}

// Round 4
// 103.840 us; speedup vs baseline: 1.6396x; 1.0758x over previous
//
#include <hip/hip_runtime.h>
#include <hip/hip_bf16.h>
#include <stdint.h>

typedef __attribute__((ext_vector_type(4))) float f32x4;
typedef __attribute__((ext_vector_type(8))) short bf16x8;
typedef __attribute__((ext_vector_type(4))) short bf16x4;
typedef __attribute__((ext_vector_type(4))) unsigned int u32x4;

__device__ __forceinline__ unsigned short f2bf_rne(float f) {
  union { float f; unsigned int u; } v; v.f = f;
  unsigned int r = v.u + 0x7FFFu + ((v.u >> 16) & 1u);
  return (unsigned short)(r >> 16);
}
__device__ __forceinline__ float bf2f(unsigned short s) {
  union { float f; unsigned int u; } v; v.u = ((unsigned int)s) << 16;
  return v.f;
}

// ---------------------------------------------------------------------------
// K1: per-batch Gram partials, split bf16 (H H^T + H L^T + L H^T), no atomics.
// G is symmetric -> only waves with wm <= wn store their 64x64 tile (10/16).
// grid (16 n-chunks, 16 b) x 1024 thr.
// ---------------------------------------------------------------------------
__global__ __launch_bounds__(1024) void k_gram(const float* __restrict__ x,
                                               float* __restrict__ Gpart) {
  __shared__ __align__(16) unsigned char lds[256 * 128];
  const int b = blockIdx.y;
  const int n0 = blockIdx.x << 8;
  const int t = threadIdx.x;
  const int lane = t & 63;
  const int w = t >> 6;
  const int wm = (w >> 2) << 6;
  const int wn = (w & 3) << 6;
  const int c_ld = t >> 2;
  const int noct = t & 3;
  const int lrow = lane & 15;
  const int lkg = lane >> 4;

  f32x4 acc[4][4];
#pragma unroll
  for (int i = 0; i < 4; i++)
#pragma unroll
    for (int j = 0; j < 4; j++) acc[i][j] = (f32x4){0.f, 0.f, 0.f, 0.f};

  const float* gx = x + (((size_t)(b * 256 + c_ld)) << 12) + n0 + (noct << 3);
  f32x4 v0 = *(const f32x4*)(gx);
  f32x4 v1 = *(const f32x4*)(gx + 4);

  for (int sub = 0; sub < 8; sub++) {
    float vv[8] = {v0[0], v0[1], v0[2], v0[3], v1[0], v1[1], v1[2], v1[3]};
    unsigned short hi[8], lo[8];
#pragma unroll
    for (int j = 0; j < 8; j++) {
      hi[j] = f2bf_rne(vv[j]);
      lo[j] = f2bf_rne(vv[j] - bf2f(hi[j]));
    }
    u32x4 hw = {(unsigned)hi[0] | ((unsigned)hi[1] << 16),
                (unsigned)hi[2] | ((unsigned)hi[3] << 16),
                (unsigned)hi[4] | ((unsigned)hi[5] << 16),
                (unsigned)hi[6] | ((unsigned)hi[7] << 16)};
    u32x4 lw = {(unsigned)lo[0] | ((unsigned)lo[1] << 16),
                (unsigned)lo[2] | ((unsigned)lo[3] << 16),
                (unsigned)lo[4] | ((unsigned)lo[5] << 16),
                (unsigned)lo[6] | ((unsigned)lo[7] << 16)};

    __syncthreads();  // previous tile's MFMA reads done before overwrite
    const int swz = (c_ld & 7) << 4;
    *(u32x4*)(lds + c_ld * 128 + (((noct << 4)) ^ swz)) = hw;       // H region
    *(u32x4*)(lds + c_ld * 128 + ((64 + (noct << 4)) ^ swz)) = lw;  // L region
    __syncthreads();

    // prefetch next sub's x under the MFMA section (T14 split)
    if (sub < 7) {
      v0 = *(const f32x4*)(gx + ((sub + 1) << 5));
      v1 = *(const f32x4*)(gx + ((sub + 1) << 5) + 4);
    }

    bf16x8 bh[4], bl[4];
#pragma unroll
    for (int nf = 0; nf < 4; nf++) {
      int col = wn + (nf << 4) + lrow;
      int cs = (col & 7) << 4;
      bh[nf] = *(const bf16x8*)(lds + col * 128 + (((lkg << 4)) ^ cs));
      bl[nf] = *(const bf16x8*)(lds + col * 128 + ((64 + (lkg << 4)) ^ cs));
    }
#pragma unroll
    for (int mf = 0; mf < 4; mf++) {
      int row = wm + (mf << 4) + lrow;
      int rs = (row & 7) << 4;
      bf16x8 ah = *(const bf16x8*)(lds + row * 128 + (((lkg << 4)) ^ rs));
      bf16x8 al = *(const bf16x8*)(lds + row * 128 + ((64 + (lkg << 4)) ^ rs));
#pragma unroll
      for (int nf = 0; nf < 4; nf++) {
        acc[mf][nf] = __builtin_amdgcn_mfma_f32_16x16x32_bf16(ah, bh[nf], acc[mf][nf], 0, 0, 0);
        acc[mf][nf] = __builtin_amdgcn_mfma_f32_16x16x32_bf16(ah, bl[nf], acc[mf][nf], 0, 0, 0);
        acc[mf][nf] = __builtin_amdgcn_mfma_f32_16x16x32_bf16(al, bh[nf], acc[mf][nf], 0, 0, 0);
      }
    }
  }

  if (wm <= wn) {  // upper-triangle tiles only (G symmetric)
    float* Gp = Gpart + (((size_t)(blockIdx.x * 16 + b)) << 16);
#pragma unroll
    for (int mf = 0; mf < 4; mf++)
#pragma unroll
      for (int nf = 0; nf < 4; nf++) {
        int col = wn + (nf << 4) + lrow;
#pragma unroll
        for (int r = 0; r < 4; r++) {
          int row = wm + (mf << 4) + (lkg << 2) + r;
          Gp[row * 256 + col] = acc[mf][nf][r];
        }
      }
  }
}

// ---------------------------------------------------------------------------
// K1b: per-(b, upper tile i<=j) block: sum 16 chunk-partials of the 64x64
// tile, write it, and (i<j) write the LDS-transposed mirror. 160 blocks.
// ---------------------------------------------------------------------------
__global__ __launch_bounds__(256) void k_reduce(const float* __restrict__ Gpart,
                                                float* __restrict__ G) {
  __shared__ float tl[64][68];
  const int bx = blockIdx.x;  // 16 b x 10 tile-pairs
  const int b = bx / 10;
  int tp = bx % 10;
  int i = 0;
  while (tp >= 4 - i) { tp -= 4 - i; ++i; }
  const int j = i + tp;
  const int t = threadIdx.x;
  const int r = t >> 2, cg = t & 3;

  f32x4 s[4];
#pragma unroll
  for (int q = 0; q < 4; q++) s[q] = (f32x4){0.f, 0.f, 0.f, 0.f};
  const float* src = Gpart + ((size_t)b << 16) + (size_t)(i * 64 + r) * 256 + j * 64 + cg * 16;
  for (int ch = 0; ch < 16; ch++) {
    const float* p = src + (((size_t)ch) << 20);
#pragma unroll
    for (int q = 0; q < 4; q++) s[q] += *(const f32x4*)(p + (q << 2));
  }
  float* dst = G + ((size_t)b << 16) + (size_t)(i * 64 + r) * 256 + j * 64 + cg * 16;
#pragma unroll
  for (int q = 0; q < 4; q++) *(f32x4*)(dst + (q << 2)) = s[q];

  if (i != j) {
#pragma unroll
    for (int q = 0; q < 4; q++) *(f32x4*)&tl[r][cg * 16 + (q << 2)] = s[q];
    __syncthreads();
    const int c2 = t >> 2, g2 = t & 3;
    float vals[16];
#pragma unroll
    for (int q = 0; q < 16; q++) vals[q] = tl[g2 * 16 + q][c2];
    float* d2 = G + ((size_t)b << 16) + (size_t)(j * 64 + c2) * 256 + i * 64 + g2 * 16;
#pragma unroll
    for (int q = 0; q < 4; q++) {
      f32x4 vv = {vals[4 * q], vals[4 * q + 1], vals[4 * q + 2], vals[4 * q + 3]};
      *(f32x4*)(d2 + (q << 2)) = vv;
    }
  }
}

// ---------------------------------------------------------------------------
// K2: T = Wq_rows·G (c-split over 8 waves; Wq via wave-uniform SCALAR loads —
// no bpermute), LDS partial-reduce; scores + softmax -> attn; Wout rows via
// readlane(A) + coalesced Wv rows. grid (8 h, 16 b, 2 dg) x 512.
// ---------------------------------------------------------------------------
__global__ __launch_bounds__(512) void k_scores(const float* __restrict__ wq,
                                                const float* __restrict__ wk,
                                                const float* __restrict__ wv,
                                                const float* __restrict__ G,
                                                float* __restrict__ attn,
                                                unsigned short* __restrict__ Wout) {
  __shared__ float part[8][16][256];  // 128 KB; part[0] becomes T after reduce
  const int h = blockIdx.x, b = blockIdx.y, dg = blockIdx.z;
  const int t = threadIdx.x, lane = t & 63;
  const int wu = __builtin_amdgcn_readfirstlane(t >> 6);  // wave id, uniform

  // ---- Phase 1: T[d][cp] = sum_c Wq[h*32+dg*16+d][c] * G[b][c][cp] ----
  const float* wqrow = wq + (size_t)(h * 32 + dg * 16) * 256 + wu * 32;  // uniform
  f32x4 tp[16];
#pragma unroll
  for (int d = 0; d < 16; d++) tp[d] = (f32x4){0.f, 0.f, 0.f, 0.f};

  const float* Gb = G + ((size_t)b << 16) + (size_t)(wu * 32) * 256 + (lane << 2);
  for (int s = 0; s < 32; s++) {
    f32x4 g = *(const f32x4*)(Gb + s * 256);
#pragma unroll
    for (int d = 0; d < 16; d++)
      tp[d] += g * wqrow[d * 256 + s];  // uniform index -> s_load (SMEM pipe)
  }
#pragma unroll
  for (int d = 0; d < 16; d++)
    *(f32x4*)&part[wu][d][lane << 2] = tp[d];
  __syncthreads();

  // in-place reduce into part[0]: each thread owns 2 f32x4 output slots
#pragma unroll
  for (int u = 0; u < 2; u++) {
    int o = t * 2 + u;  // [0,1024) = 16 d x 64 quads
    int d = o >> 6, q = (o & 63) << 2;
    f32x4 s = *(f32x4*)&part[0][d][q];
#pragma unroll
    for (int w2 = 1; w2 < 8; w2++) s += *(f32x4*)&part[w2][d][q];
    *(f32x4*)&part[0][d][q] = s;
  }
  __syncthreads();
  const float* Tb = &part[0][0][0];

  // ---- Phase 2: scores + softmax (thread = (dls = t>>5, es = t&31)) ----
  const int dls = t >> 5, es = t & 31;
  f32x4 sa = {0.f, 0.f, 0.f, 0.f};
  const float* Tr = Tb + dls * 256;
  const float* wkr = wk + (size_t)(h * 32 + es) * 256;
  for (int c4 = 0; c4 < 64; c4++)
    sa += *(const f32x4*)(Tr + (c4 << 2)) * *(const f32x4*)(wkr + (c4 << 2));
  float s = (sa[0] + sa[1] + sa[2] + sa[3]) * 0.35355339059327379f;

  float m = s;
#pragma unroll
  for (int off = 1; off < 32; off <<= 1) m = fmaxf(m, __shfl_xor(m, off));
  float p = expf(s - m);
  float su = p;
#pragma unroll
  for (int off = 1; off < 32; off <<= 1) su += __shfl_xor(su, off);
  float a = p / su;
  attn[(((b * 8 + h) * 32) + dg * 16 + dls) * 32 + es] = a;

  // ---- Phase 3: wave wu owns rows {2wu, 2wu+1}; A broadcast via readlane ----
  f32x4 o0 = {0.f, 0.f, 0.f, 0.f}, o1 = {0.f, 0.f, 0.f, 0.f};
  const float* wvh = wv + (size_t)(h * 32) * 256 + (lane << 2);
#pragma unroll
  for (int e = 0; e < 32; e++) {
    float a0 = __shfl(a, e);
    float a1 = __shfl(a, 32 + e);
    f32x4 vv = *(const f32x4*)(wvh + e * 256);
    o0 += vv * a0;
    o1 += vv * a1;
  }
  const int d0 = dg * 16 + 2 * wu;
  const int co0 = d0 * 8 + h, co1 = (d0 + 1) * 8 + h;
  o0 += *(const f32x4*)(wv + (size_t)co0 * 256 + (lane << 2));
  o1 += *(const f32x4*)(wv + (size_t)co1 * 256 + (lane << 2));
  bf16x4 p0, p1;
#pragma unroll
  for (int j = 0; j < 4; j++) {
    p0[j] = (short)f2bf_rne(o0[j]);
    p1[j] = (short)f2bf_rne(o1[j]);
  }
  *(bf16x4*)(Wout + ((size_t)(b * 256 + co0) << 8) + (lane << 2)) = p0;
  *(bf16x4*)(Wout + ((size_t)(b * 256 + co1) << 8) + (lane << 2)) = p1;
}

// ---------------------------------------------------------------------------
// K3: out[b] = W_out_b (bf16) x bf16(x[b]), fp32 out. x read fp32 (L3-hot),
// converted in-kernel, ds_write_b128 linear; tr_b16 B-frag path (verified).
// grid (32 n-chunks, 16 b) x 512 thr.
// ---------------------------------------------------------------------------
__global__ __launch_bounds__(512) void k_out(const float* __restrict__ x,
                                             const unsigned short* __restrict__ Wout,
                                             float* __restrict__ out) {
  __shared__ __align__(16) unsigned short Bt[4096];  // 32c x 128n, subtiled
  const int b = blockIdx.y;
  const int nb = blockIdx.x << 7;
  const int t = threadIdx.x;
  const int lane = t & 63;
  const int w = t >> 6;
  const int wm = (w >> 1) << 6;
  const int wn = (w & 1) << 6;
  const int lrow = lane & 15;
  const int lkg = lane >> 4;

  f32x4 acc[4][4];
#pragma unroll
  for (int i = 0; i < 4; i++)
#pragma unroll
    for (int j = 0; j < 4; j++) acc[i][j] = (f32x4){0.f, 0.f, 0.f, 0.f};

  // staging lane map (m173 pattern): linear LDS dest <- permuted global src
  const int pos = lane >> 3;
  const int cblk = 2 * (pos & 3) + (pos >> 2);  // even cblks first, then odd
  const int ctil = cblk * 4 + ((lane & 7) >> 1);
  const int noff = (lane & 1) << 3;
  const float* gxb = x + (((size_t)b) << 20) + (size_t)ctil * 4096 + nb + (w << 4) + noff;
  const unsigned int bt0 = (unsigned int)(uintptr_t)(&Bt[0]);

  f32x4 xa = *(const f32x4*)(gxb);
  f32x4 xb = *(const f32x4*)(gxb + 4);

  for (int kt = 0; kt < 8; kt++) {
    __syncthreads();  // prior MFMA reads of Bt done
    bf16x8 pk;
#pragma unroll
    for (int j = 0; j < 4; j++) {
      pk[j] = (short)f2bf_rne(xa[j]);
      pk[4 + j] = (short)f2bf_rne(xb[j]);
    }
    *(bf16x8*)(Bt + (w << 9) + (lane << 3)) = pk;
    __syncthreads();

    if (kt < 7) {  // prefetch next k-tile under MFMA
      const float* nx = gxb + (((size_t)(kt + 1)) << 17);
      xa = *(const f32x4*)(nx);
      xb = *(const f32x4*)(nx + 4);
    }

    bf16x8 afr[4];
    const unsigned short* wrow = Wout + (((size_t)(b * 256)) << 8) + kt * 32 + (lkg << 3);
#pragma unroll
    for (int mf = 0; mf < 4; mf++) {
      int co = wm + (mf << 4) + lrow;
      afr[mf] = *(const bf16x8*)(wrow + ((size_t)co << 8));
    }

    bf16x4 t0[4], t1[4];
#pragma unroll
    for (int nf = 0; nf < 4; nf++) {
      unsigned int base = bt0 + (unsigned int)((((wn >> 4) + nf)) << 10) + (lane << 3);
      asm volatile("ds_read_b64_tr_b16 %0, %1" : "=v"(t0[nf]) : "v"(base) : "memory");
      asm volatile("ds_read_b64_tr_b16 %0, %1 offset:512" : "=v"(t1[nf]) : "v"(base) : "memory");
    }
    asm volatile("s_waitcnt lgkmcnt(0)" ::: "memory");
    __builtin_amdgcn_sched_barrier(0);

    bf16x8 bfr[4];
#pragma unroll
    for (int nf = 0; nf < 4; nf++) {
      bfr[nf][0] = t0[nf][0]; bfr[nf][1] = t0[nf][1];
      bfr[nf][2] = t0[nf][2]; bfr[nf][3] = t0[nf][3];
      bfr[nf][4] = t1[nf][0]; bfr[nf][5] = t1[nf][1];
      bfr[nf][6] = t1[nf][2]; bfr[nf][7] = t1[nf][3];
    }
#pragma unroll
    for (int mf = 0; mf < 4; mf++)
#pragma unroll
      for (int nf = 0; nf < 4; nf++)
        acc[mf][nf] = __builtin_amdgcn_mfma_f32_16x16x32_bf16(afr[mf], bfr[nf], acc[mf][nf], 0, 0, 0);
  }

  float* ob = out + (((size_t)b) << 20) + nb;
#pragma unroll
  for (int mf = 0; mf < 4; mf++)
#pragma unroll
    for (int nf = 0; nf < 4; nf++) {
      int col = wn + (nf << 4) + lrow;
#pragma unroll
      for (int r = 0; r < 4; r++) {
        int row = wm + (mf << 4) + (lkg << 2) + r;
        ob[((size_t)row << 12) + col] = acc[mf][nf][r];
      }
    }
}

// ---------------------------------------------------------------------------
extern "C" void kernel_launch(void* const* d_in, const int* in_sizes, int n_in,
                              void* d_out, int out_size, void* d_ws, size_t ws_size,
                              hipStream_t stream) {
  const float* x = (const float*)d_in[0];
  const float* wq = (const float*)d_in[1];
  const float* wk = (const float*)d_in[2];
  const float* wv = (const float*)d_in[3];
  float* out = (float*)d_out;
  float* attn = out + (size_t)16 * 256 * 4096;

  // Gram partials live in the (dead-until-K3) out region: 16 x 4 MB = exactly
  // the 67.1 MB out area; attn tail is disjoint. All consumed before K3 writes.
  float* Gpart = out;

  char* ws = (char*)d_ws;
  float* G = (float*)ws;                                     // 4 MB
  unsigned short* Wout = (unsigned short*)(ws + (4 << 20));  // 2 MB

  k_gram<<<dim3(16, 16), dim3(1024), 0, stream>>>(x, Gpart);
  k_reduce<<<dim3(160), dim3(256), 0, stream>>>(Gpart, G);
  k_scores<<<dim3(8, 16, 2), dim3(512), 0, stream>>>(wq, wk, wv, G, attn, Wout);
  k_out<<<dim3(32, 16), dim3(512), 0, stream>>>(x, Wout, out);
}